// Round 22
// baseline (258.130 us; speedup 1.0000x reference)
//
#include <hip/hip_runtime.h>

typedef unsigned short ushort_t;
typedef __attribute__((ext_vector_type(8))) _Float16 f16x8;
typedef __attribute__((ext_vector_type(4))) float f32x4;
typedef __attribute__((ext_vector_type(4))) unsigned int u32x4;
typedef __attribute__((ext_vector_type(2))) unsigned long long u64x2;

#define ROWB 576   // 288 cols fp16; unified swizzle in [0,512): phys = log ^ ((row&7)<<4) ^ (((log>>7)&3)<<4)
#define BUFB (64*ROWB)   // 36864 B: ONE act buffer (in-place) -> 3 blocks/CU

__device__ __forceinline__ ushort_t f2h(float x){ _Float16 h=(_Float16)x; return __builtin_bit_cast(ushort_t,h); }
__device__ __forceinline__ float h2f(ushort_t u){ return (float)__builtin_bit_cast(_Float16,u); }
__device__ __forceinline__ unsigned int pkrtz(float lo, float hi){
    return __builtin_bit_cast(unsigned int, __builtin_amdgcn_cvt_pkrtz(lo, hi));
}
__device__ __forceinline__ unsigned int pk_add2(unsigned int a, unsigned int b){
    unsigned int r; asm("v_pk_add_f16 %0, %1, %2" : "=v"(r) : "v"(a), "v"(b)); return r;
}
__device__ __forceinline__ unsigned int pk_relu2(unsigned int a){
    unsigned int r; asm("v_pk_max_f16 %0, %1, %2" : "=v"(r) : "v"(a), "v"(0u)); return r;
}

// physical position of logical channel c within its 32-channel block:
// slot group g = (c%16)/4 holds logical k = {4g..4g+3, 16+4g..16+4g+3} contiguously (16B)
__device__ __forceinline__ int permc(int c){
    return (c & ~31) + (((c >> 2) & 3) << 3) + (c & 3) + (((c >> 4) & 1) << 2);
}

// ---------------- conv 3x3, 3->256, SAME ----------------
__global__ __launch_bounds__(256) void conv_k(const float* __restrict__ inp,
        const float* __restrict__ w, const float* __restrict__ bias,
        ushort_t* __restrict__ feat)
{
    __shared__ float sw_[6912];
    __shared__ float patch[27];
    int t = threadIdx.x;
    int b = blockIdx.x >> 12, p = blockIdx.x & 4095;
    int y = p >> 6, x = p & 63;
    for (int i = t; i < 6912; i += 256) sw_[i] = w[i];
    if (t < 27){
        int ci = t/9, r = t%9, dy = r/3, dx = r%3;
        int yy = y+dy-1, xx = x+dx-1;
        patch[t] = (yy>=0 && yy<64 && xx>=0 && xx<64) ? inp[((b*3+ci)<<12)+(yy<<6)+xx] : 0.f;
    }
    __syncthreads();
    float acc = bias[t];
    #pragma unroll
    for (int j = 0; j < 27; ++j) acc += patch[j]*sw_[t*27+j];
    feat[(((b<<12)+p)<<8) + permc(t)] = f2h(acc);
}

// ---------------- pack weights into MFMA fragment order (fp16) ----------------
// layout: [layer][kc][ntile(16)][lane(64)][8], layer0: kc 0..8 (k 256..259 = extra dims, rest 0)
__global__ __launch_bounds__(256) void pack_k(const float* __restrict__ w_in,
        const float* __restrict__ w_hid, ushort_t* __restrict__ packW)
{
    int i = blockIdx.x*256 + threadIdx.x;
    if (i >= 270336) return;
    int layer, rem;
    if (i < 73728){ layer = 0; rem = i; }
    else { int j = i - 73728; layer = 1 + (j >> 16); rem = j & 65535; }
    int j8 = rem & 7, frag = rem >> 3;
    int lane = frag & 63, kt = frag >> 6;
    int kc = kt >> 4, nt = kt & 15;
    int k = kc*32 + ((lane>>4)<<2) + (j8 & 3) + ((j8 >> 2) << 4);
    int n = (nt<<4) + (lane & 15);
    float val;
    if (layer == 0) val = (k < 260) ? w_in[k*256 + n] : 0.f;
    else            val = w_hid[((layer-1)*256 + k)*256 + n];
    packW[i] = f2h(val);
}

// ---------------- L0 precompute: h0 = feat . W_in[0:256]  (per feature pixel) ------------
__global__ __launch_bounds__(256) void l0pre_k(const ushort_t* feat,
        const ushort_t* __restrict__ packW, ushort_t* h0)
{
    __shared__ __align__(16) char buf[BUFB];
    const int t = threadIdx.x, lane = t & 63, wave = t >> 6;
    const int b = blockIdx.x >> 6, p0 = (blockIdx.x & 63) << 6;
    {
        int m = t >> 2, q = t & 3;
        char* drow = buf + m*ROWB;
        int sw = ((m & 7) << 4) ^ (q << 4);   // unified swizzle: q = log>>7
        const u64x2* src = (const u64x2*)(feat + (((b<<12) + p0 + m)<<8) + q*64);
        #pragma unroll
        for (int c = 0; c < 8; ++c)
            *(u64x2*)(drow + ((q*128 + c*16) ^ sw)) = src[c];
    }
    __syncthreads();
    const int l15 = lane & 15, g = lane >> 4;
    const int swz = (l15 & 7) << 4;
    f32x4 acc[4][4];
    #pragma unroll
    for (int nt = 0; nt < 4; ++nt)
        #pragma unroll
        for (int mg = 0; mg < 4; ++mg) acc[mg][nt] = (f32x4){0.f,0.f,0.f,0.f};
    const int lofs = (wave*256 + lane)*8;
    f16x8 wA[4], wB[4], aP0[4], aP1[4];
    #pragma unroll
    for (int nt = 0; nt < 4; ++nt){
        wA[nt] = *(const f16x8*)(packW + lofs + nt*512);
        wB[nt] = *(const f16x8*)(packW + lofs + 8192 + nt*512);
    }
    {
        const int o2 = (g*16) ^ swz;
        #pragma unroll
        for (int mg = 0; mg < 4; ++mg)
            aP0[mg] = *(const f16x8*)(buf + (mg*16 + l15)*ROWB + o2);
    }
    #pragma unroll
    for (int kc = 0; kc < 8; ++kc){
        if (kc + 1 < 8){
            const int o2 = ((kc + 1)*64 + g*16) ^ swz ^ ((((kc + 1) >> 1) & 3) << 4);
            if ((kc & 1) == 0){
                #pragma unroll
                for (int mg = 0; mg < 4; ++mg)
                    aP1[mg] = *(const f16x8*)(buf + (mg*16 + l15)*ROWB + o2);
            } else {
                #pragma unroll
                for (int mg = 0; mg < 4; ++mg)
                    aP0[mg] = *(const f16x8*)(buf + (mg*16 + l15)*ROWB + o2);
            }
        }
        if ((kc & 1) == 0){
            #pragma unroll
            for (int mg = 0; mg < 4; ++mg)
                #pragma unroll
                for (int nt = 0; nt < 4; ++nt)
                    acc[mg][nt] = __builtin_amdgcn_mfma_f32_16x16x32_f16(wA[nt], aP0[mg], acc[mg][nt], 0, 0, 0);
        } else {
            #pragma unroll
            for (int mg = 0; mg < 4; ++mg)
                #pragma unroll
                for (int nt = 0; nt < 4; ++nt)
                    acc[mg][nt] = __builtin_amdgcn_mfma_f32_16x16x32_f16(wB[nt], aP1[mg], acc[mg][nt], 0, 0, 0);
        }
        if (kc + 2 < 8){
            const ushort_t* pf = packW + lofs + (kc + 2)*8192;
            if ((kc & 1) == 0){
                #pragma unroll
                for (int nt = 0; nt < 4; ++nt) wA[nt] = *(const f16x8*)(pf + nt*512);
            } else {
                #pragma unroll
                for (int nt = 0; nt < 4; ++nt) wB[nt] = *(const f16x8*)(pf + nt*512);
            }
        }
    }
    // store h0 (NO bias, NO relu): global permc'd rows, unswizzled chunk positions
    #pragma unroll
    for (int mg = 0; mg < 4; ++mg){
        char* row = (char*)(h0 + (((b<<12) + p0 + mg*16 + l15)<<8));
        #pragma unroll
        for (int i = 0; i < 2; ++i){
            const int kb = 2*wave + i;
            f32x4 a0 = acc[mg][2*i], a1 = acc[mg][2*i + 1];
            u32x4 st;
            st[0] = pkrtz(a0[0], a0[1]);
            st[1] = pkrtz(a0[2], a0[3]);
            st[2] = pkrtz(a1[0], a1[1]);
            st[3] = pkrtz(a1[2], a1[3]);
            *(u32x4*)(row + kb*64 + 16*g) = st;
        }
    }
}

// ---------------- fused MLP layer, TRANSPOSED, IN-PLACE single buffer -------------------
template<int KC, bool HAS_NEXT, bool STORE>
__device__ __forceinline__ void mlp_layer(const ushort_t* __restrict__ wfrag,
        const ushort_t* __restrict__ nextw,
        const float* __restrict__ bias, char* __restrict__ buf,
        int lane, int wave, f16x8 (&wP0)[4], f16x8 (&wP1)[4], f32x4 (&acc)[4][4])
{
    const int l15 = lane & 15, g = lane >> 4;
    const int swz  = (l15 & 7) << 4;
    const int aoffg = g*16;
    #pragma unroll
    for (int nt = 0; nt < 4; ++nt){
        f32x4 bv = *(const f32x4*)(bias + (wave*4 + nt)*16 + 4*g);
        #pragma unroll
        for (int mg = 0; mg < 4; ++mg) acc[mg][nt] = bv;
    }
    const int lofs = (wave*4*64 + lane)*8;
    f16x8 aP0[4], aP1[4];
    {
        const int o2 = aoffg ^ swz;
        #pragma unroll
        for (int mg = 0; mg < 4; ++mg)
            aP0[mg] = *(const f16x8*)(buf + (mg*16 + l15)*ROWB + o2);
    }
    #pragma unroll
    for (int kc = 0; kc < KC; ++kc){
        const ushort_t* pfw = nullptr;
        if (kc + 2 < KC)   pfw = wfrag + lofs + (kc + 2)*8192;
        else if (HAS_NEXT) pfw = nextw + lofs + (kc + 2 - KC)*8192;
        const bool la = (kc + 1 < KC);
        if (la){
            const int o2 = ((kc + 1)*64 + aoffg) ^ swz ^ ((((kc + 1) >> 1) & 3) << 4);
            if ((kc & 1) == 0){
                #pragma unroll
                for (int mg = 0; mg < 4; ++mg)
                    aP1[mg] = *(const f16x8*)(buf + (mg*16 + l15)*ROWB + o2);
            } else {
                #pragma unroll
                for (int mg = 0; mg < 4; ++mg)
                    aP0[mg] = *(const f16x8*)(buf + (mg*16 + l15)*ROWB + o2);
            }
        }
        __builtin_amdgcn_s_setprio(1);
        if ((kc & 1) == 0){
            #pragma unroll
            for (int mg = 0; mg < 4; ++mg)
                #pragma unroll
                for (int nt = 0; nt < 4; ++nt)
                    acc[mg][nt] = __builtin_amdgcn_mfma_f32_16x16x32_f16(wP0[nt], aP0[mg], acc[mg][nt], 0, 0, 0);
        } else {
            #pragma unroll
            for (int mg = 0; mg < 4; ++mg)
                #pragma unroll
                for (int nt = 0; nt < 4; ++nt)
                    acc[mg][nt] = __builtin_amdgcn_mfma_f32_16x16x32_f16(wP1[nt], aP1[mg], acc[mg][nt], 0, 0, 0);
        }
        __builtin_amdgcn_s_setprio(0);
        if (pfw){
            if ((kc & 1) == 0){
                #pragma unroll
                for (int nt = 0; nt < 4; ++nt) wP0[nt] = *(const f16x8*)(pfw + nt*512);
            } else {
                #pragma unroll
                for (int nt = 0; nt < 4; ++nt) wP1[nt] = *(const f16x8*)(pfw + nt*512);
            }
        }
    }
    __syncthreads();   // all waves' reads of buf drained
    if (STORE){
        const int wsw = swz ^ (wave << 4);   // log>>7 = kb>>1 = wave (const per wave)
        #pragma unroll
        for (int mg = 0; mg < 4; ++mg){
            char* row = buf + (mg*16 + l15)*ROWB;
            #pragma unroll
            for (int i = 0; i < 2; ++i){
                const int kb = 2*wave + i;
                f32x4 a0 = acc[mg][2*i], a1 = acc[mg][2*i + 1];
                u32x4 st;
                st[0] = pk_relu2(pkrtz(a0[0], a0[1]));
                st[1] = pk_relu2(pkrtz(a0[2], a0[3]));
                st[2] = pk_relu2(pkrtz(a1[0], a1[1]));
                st[3] = pk_relu2(pkrtz(a1[2], a1[3]));
                *(u32x4*)(row + ((kb*64 + 16*g) ^ wsw)) = st;
            }
        }
        __syncthreads();   // stores visible before next layer reads
    }
}

// ---------------- main fused kernel: 16 pixels x 4 corners per block; in-kernel combine ----
// Row m = corner(m>>4)*16 + pixel(m&15). The MLP path is row-agnostic; the out-layer's mg
// index becomes the corner, so each pixel's 4 preds are block-local -> ensemble+softmax fused.
__global__ __launch_bounds__(256, 3) void liif_k(
        const float* __restrict__ coord, const float* __restrict__ cell,
        const float* __restrict__ b_in, const float* __restrict__ b_hid,
        const float* __restrict__ w_out, const float* __restrict__ b_out,
        const ushort_t* __restrict__ h0, const ushort_t* __restrict__ packW,
        float* __restrict__ out)
{
    __shared__ __align__(16) char buf[BUFB];   // 36864 B -> 3 blocks/CU
    __shared__ float sarea[64];
    const int t = threadIdx.x, lane = t & 63, wave = t >> 6;   // wave in [0,4)
    const int bi = blockIdx.x;
    const int b = bi >> 12;
    const int t12 = bi & 4095;
    const int th = t12 >> 6, tw = t12 & 63;   // 64x64 tiles of 4x4 pixels

    // --- prologue loads: L0-extras weights (kc8) + L1 kc0/kc1 ---
    f16x8 wX[4], wA[4], wB[4];
    const ushort_t* L1 = packW + 73728;
    {
        const int lofs = (wave*256 + lane)*8;
        #pragma unroll
        for (int nt = 0; nt < 4; ++nt){
            wX[nt] = *(const f16x8*)(packW + 65536 + lofs + nt*512);
            wA[nt] = *(const f16x8*)(L1 + lofs + nt*512);
            wB[nt] = *(const f16x8*)(L1 + 8192 + nt*512 + lofs);
        }
    }

    // --- setup: gather h0 rows + extras + area (4 threads per row, 128B each) ---
    {
        int m = t >> 2, q = t & 3;
        int v = m >> 4, pix = m & 15;
        int qh = th*4 + (pix >> 2), qw = tw*4 + (pix & 3);
        int cidx = (((b<<8) + qh)<<8) + qw;
        float c0 = coord[cidx*2], c1 = coord[cidx*2 + 1];
        float ch = c0 + ((v & 2) ? 0.015625f : -0.015625f); ch = ch + 1e-6f;
        ch = fminf(fmaxf(ch, -1.f + 1e-6f), 1.f - 1e-6f);
        float cw = c1 + ((v & 1) ? 0.015625f : -0.015625f); cw = cw + 1e-6f;
        cw = fminf(fmaxf(cw, -1.f + 1e-6f), 1.f - 1e-6f);
        int ih = (int)floorf((ch + 1.f)*64.f*0.5f); ih = ih < 0 ? 0 : (ih > 63 ? 63 : ih);
        int iw = (int)floorf((cw + 1.f)*64.f*0.5f); iw = iw < 0 ? 0 : (iw > 63 ? 63 : iw);
        char* drow = buf + m*ROWB;
        int sw = ((m & 7) << 4) ^ (q << 4);   // unified swizzle: q = log>>7
        const u64x2* src = (const u64x2*)(h0 + ((((b<<6) + ih)<<6) + iw)*256 + q*64);
        #pragma unroll
        for (int c = 0; c < 8; ++c)
            *(u64x2*)(drow + ((q*128 + c*16) ^ sw)) = src[c];
        if (q == 0){
            float qch = (2.f*(float)ih + 1.f)*(1.f/64.f) - 1.f;
            float qcw = (2.f*(float)iw + 1.f)*(1.f/64.f) - 1.f;
            float relh = (c0 - qch)*64.f, relw = (c1 - qcw)*64.f;
            float rch = cell[b*2]*64.f, rcw = cell[b*2 + 1]*64.f;
            unsigned long long ex = (unsigned long long)f2h(relh)
                | ((unsigned long long)f2h(relw) << 16)
                | ((unsigned long long)f2h(rch)  << 32)
                | ((unsigned long long)f2h(rcw)  << 48);
            u64x2 e; e[0] = ex; e[1] = 0;
            u64x2 z; z[0] = 0;  z[1] = 0;
            int sw2 = (m & 3) << 4;
            #pragma unroll
            for (int c = 1; c < 4; ++c)
                *(u64x2*)(drow + 512 + ((c*16) ^ sw2)) = z;
            *(u64x2*)(drow + 512 + sw2) = e;
            sarea[m] = fabsf(relh*relw) + 1e-9f;
        }
    }
    __syncthreads();

    f32x4 acc[4][4];
    // --- L0': bias + extras-MFMA (1 kc) + packed-fp16 h0 add + ReLU, store in place ---
    {
        const int l15 = lane & 15, g = lane >> 4;
        const int swz  = (l15 & 7) << 4;
        const int swz2 = (l15 & 3) << 4;
        const int wsw  = swz ^ (wave << 4);
        #pragma unroll
        for (int nt = 0; nt < 4; ++nt){
            f32x4 bv = *(const f32x4*)(b_in + (wave*4 + nt)*16 + 4*g);
            #pragma unroll
            for (int mg = 0; mg < 4; ++mg) acc[mg][nt] = bv;
        }
        f16x8 af[4];
        {
            const int o2 = 512 + ((g*16) ^ swz2);
            #pragma unroll
            for (int mg = 0; mg < 4; ++mg)
                af[mg] = *(const f16x8*)(buf + (mg*16 + l15)*ROWB + o2);
        }
        #pragma unroll
        for (int mg = 0; mg < 4; ++mg)
            #pragma unroll
            for (int nt = 0; nt < 4; ++nt)
                acc[mg][nt] = __builtin_amdgcn_mfma_f32_16x16x32_f16(wX[nt], af[mg], acc[mg][nt], 0, 0, 0);
        #pragma unroll
        for (int mg = 0; mg < 4; ++mg){
            char* row = buf + (mg*16 + l15)*ROWB;
            #pragma unroll
            for (int i = 0; i < 2; ++i){
                const int kb = 2*wave + i;
                u32x4 hv = *(const u32x4*)(row + ((kb*64 + 16*g) ^ wsw));
                f32x4 a0 = acc[mg][2*i], a1 = acc[mg][2*i + 1];
                u32x4 st;
                st[0] = pk_relu2(pk_add2(pkrtz(a0[0], a0[1]), hv[0]));
                st[1] = pk_relu2(pk_add2(pkrtz(a0[2], a0[3]), hv[1]));
                st[2] = pk_relu2(pk_add2(pkrtz(a1[0], a1[1]), hv[2]));
                st[3] = pk_relu2(pk_add2(pkrtz(a1[2], a1[3]), hv[3]));
                *(u32x4*)(row + ((kb*64 + 16*g) ^ wsw)) = st;
            }
        }
        __syncthreads();
    }

    // --- 3 MFMA layers (in-place; even KC -> no parity swap) ---
    const ushort_t* L2 = packW + 73728 + 65536;
    const ushort_t* L3 = packW + 73728 + 131072;
    mlp_layer<8, true , true >(L1, L2,      b_hid,       buf, lane, wave, wA, wB, acc);
    mlp_layer<8, true , true >(L2, L3,      b_hid + 256, buf, lane, wave, wA, wB, acc);
    mlp_layer<8, false, false>(L3, nullptr, b_hid + 512, buf, lane, wave, wA, wB, acc);

    // --- fused out layer + ensemble combine + softmax ---
    {
        const int l15 = lane & 15, g = lane >> 4;
        float s0[4] = {0.f,0.f,0.f,0.f}, s1[4] = {0.f,0.f,0.f,0.f};
        #pragma unroll
        for (int j = 0; j < 4; ++j){
            int nb = wave*64 + j*16 + 4*g;
            f32x4 w01 = *(const f32x4*)(w_out + nb*2);
            f32x4 w23 = *(const f32x4*)(w_out + nb*2 + 4);
            #pragma unroll
            for (int mg = 0; mg < 4; ++mg){
                float v0 = fmaxf(acc[mg][j][0], 0.f);
                float v1 = fmaxf(acc[mg][j][1], 0.f);
                float v2 = fmaxf(acc[mg][j][2], 0.f);
                float v3 = fmaxf(acc[mg][j][3], 0.f);
                s0[mg] += v0*w01[0] + v1*w01[2] + v2*w23[0] + v3*w23[2];
                s1[mg] += v0*w01[1] + v1*w01[3] + v2*w23[1] + v3*w23[3];
            }
        }
        float2* stage  = (float2*)buf;          // [wave][mg*16+pix], 2 KB
        float2* stage2 = (float2*)(buf + 2048); // [mg*16+pix], 512 B
        #pragma unroll
        for (int mg = 0; mg < 4; ++mg){
            s0[mg] += __shfl_xor(s0[mg], 16); s0[mg] += __shfl_xor(s0[mg], 32);
            s1[mg] += __shfl_xor(s1[mg], 16); s1[mg] += __shfl_xor(s1[mg], 32);
            if (lane < 16){
                float2 pr; pr.x = s0[mg]; pr.y = s1[mg];
                stage[wave*64 + mg*16 + l15] = pr;
            }
        }
        __syncthreads();
        if (t < 64){
            float2 p0 = stage[t], p1 = stage[64 + t], p2 = stage[128 + t], p3 = stage[192 + t];
            float2 pr;
            pr.x = p0.x + p1.x + p2.x + p3.x;
            pr.y = p0.y + p1.y + p2.y + p3.y;
            stage2[t] = pr;   // full pred for (corner t>>4, pixel t&15), no b_out yet
        }
        __syncthreads();
        if (t < 16){
            float2 pv[4]; float a[4];
            #pragma unroll
            for (int v = 0; v < 4; ++v){
                pv[v] = stage2[v*16 + t];
                a[v]  = sarea[v*16 + t];
            }
            float tot = a[0] + a[1] + a[2] + a[3];
            float w0 = a[3]/tot, w1 = a[2]/tot, w2 = a[1]/tot, w3 = a[0]/tot;
            float r0 = pv[0].x*w0 + pv[1].x*w1 + pv[2].x*w2 + pv[3].x*w3 + b_out[0];
            float r1 = pv[0].y*w0 + pv[1].y*w1 + pv[2].y*w2 + pv[3].y*w3 + b_out[1];
            float mx = fmaxf(r0, r1);
            float e0 = expf(r0 - mx), e1 = expf(r1 - mx);
            float inv = 1.f/(e0 + e1);
            int qh = th*4 + (t >> 2), qw = tw*4 + (t & 3);
            int qidx = (qh << 8) + qw;
            out[(b<<17) + qidx]         = e0*inv;
            out[(b<<17) + 65536 + qidx] = e1*inv;
        }
    }
}

extern "C" void kernel_launch(void* const* d_in, const int* in_sizes, int n_in,
                              void* d_out, int out_size, void* d_ws, size_t ws_size,
                              hipStream_t stream)
{
    const float* inp   = (const float*)d_in[0];
    const float* coord = (const float*)d_in[1];
    const float* cell  = (const float*)d_in[2];
    const float* convw = (const float*)d_in[3];
    const float* convb = (const float*)d_in[4];
    const float* w_in  = (const float*)d_in[5];
    const float* b_in  = (const float*)d_in[6];
    const float* w_hid = (const float*)d_in[7];
    const float* b_hid = (const float*)d_in[8];
    const float* w_out = (const float*)d_in[9];
    const float* b_out = (const float*)d_in[10];
    (void)in_sizes; (void)n_in; (void)out_size; (void)ws_size;

    char* ws = (char*)d_ws;
    ushort_t* feat  = (ushort_t*)ws;                                  // 4,194,304 B (reused as h0)
    ushort_t* packW = (ushort_t*)(ws + 4194304);                      //   540,672 B
    float* out = (float*)d_out;

    pack_k<<<dim3(1056), dim3(256), 0, stream>>>(w_in, w_hid, packW);
    conv_k<<<dim3(8192), dim3(256), 0, stream>>>(inp, convw, convb, feat);
    l0pre_k<<<dim3(128), dim3(256), 0, stream>>>(feat, packW, feat);   // h0 in-place
    liif_k<<<dim3(8192), dim3(256), 0, stream>>>(coord, cell, b_in, b_hid,
                                                 w_out, b_out, feat, packW, out);
}

// Round 23
// 239.435 us; speedup vs baseline: 1.0781x; 1.0781x over previous
//
#include <hip/hip_runtime.h>

typedef unsigned short ushort_t;
typedef __attribute__((ext_vector_type(8))) _Float16 f16x8;
typedef __attribute__((ext_vector_type(4))) float f32x4;
typedef __attribute__((ext_vector_type(4))) unsigned int u32x4;
typedef __attribute__((ext_vector_type(2))) unsigned long long u64x2;

#define ROWB 576   // 288 cols fp16; unified swizzle in [0,512): phys = log ^ ((row&7)<<4) ^ (((log>>7)&3)<<4)
#define BUFB (64*ROWB)   // 36864 B: ONE act buffer (in-place) -> 3 blocks/CU

__device__ __forceinline__ ushort_t f2h(float x){ _Float16 h=(_Float16)x; return __builtin_bit_cast(ushort_t,h); }
__device__ __forceinline__ float h2f(ushort_t u){ return (float)__builtin_bit_cast(_Float16,u); }
__device__ __forceinline__ unsigned int pkrtz(float lo, float hi){
    return __builtin_bit_cast(unsigned int, __builtin_amdgcn_cvt_pkrtz(lo, hi));
}
__device__ __forceinline__ unsigned int pk_add2(unsigned int a, unsigned int b){
    unsigned int r; asm("v_pk_add_f16 %0, %1, %2" : "=v"(r) : "v"(a), "v"(b)); return r;
}
__device__ __forceinline__ unsigned int pk_relu2(unsigned int a){
    unsigned int r; asm("v_pk_max_f16 %0, %1, %2" : "=v"(r) : "v"(a), "v"(0u)); return r;
}

// physical position of logical channel c within its 32-channel block:
// slot group g = (c%16)/4 holds logical k = {4g..4g+3, 16+4g..16+4g+3} contiguously (16B)
__device__ __forceinline__ int permc(int c){
    return (c & ~31) + (((c >> 2) & 3) << 3) + (c & 3) + (((c >> 4) & 1) << 2);
}

// ---------------- pack weights into MFMA fragment order (fp16) ----------------
// [0,73728): layer0 (kc 0..8; k 256..259 = extras, rest 0)
// [73728,270336): layers 1..3
// [270336,278528): conv 3x3x3 weights as one K=32 kc (k>=27 zero)
__global__ __launch_bounds__(256) void pack_k(const float* __restrict__ w_in,
        const float* __restrict__ w_hid, const float* __restrict__ convw,
        ushort_t* __restrict__ packW)
{
    int i = blockIdx.x*256 + threadIdx.x;
    if (i >= 278528) return;
    if (i >= 270336){
        int j = i - 270336;
        int j8 = j & 7, frag = j >> 3;
        int lane = frag & 63, nt = frag >> 6;          // nt 0..15
        int k = ((lane>>4)<<2) + (j8 & 3) + ((j8 >> 2) << 4);   // K=32 slot
        int n = (nt<<4) + (lane & 15);
        packW[i] = f2h(k < 27 ? convw[n*27 + k] : 0.f);
        return;
    }
    int layer, rem;
    if (i < 73728){ layer = 0; rem = i; }
    else { int j = i - 73728; layer = 1 + (j >> 16); rem = j & 65535; }
    int j8 = rem & 7, frag = rem >> 3;
    int lane = frag & 63, kt = frag >> 6;
    int kc = kt >> 4, nt = kt & 15;
    int k = kc*32 + ((lane>>4)<<2) + (j8 & 3) + ((j8 >> 2) << 4);
    int n = (nt<<4) + (lane & 15);
    float val;
    if (layer == 0) val = (k < 260) ? w_in[k*256 + n] : 0.f;
    else            val = w_hid[((layer-1)*256 + k)*256 + n];
    packW[i] = f2h(val);
}

// ---------------- fused conv(3->256, SAME) + L0 precompute: h0 = feat.W_in[0:256] --------
// 64 pixels (8x8 tile) per block. im2col K=32 (27 real) -> 1-kc conv MFMA (bias folded)
// -> feat in LDS (no relu) -> 8-kc L0 GEMM -> h0 global (permc'd rows, linear chunks).
__global__ __launch_bounds__(256) void convl0_k(const float* __restrict__ inp,
        const float* __restrict__ convb, const ushort_t* __restrict__ packW,
        ushort_t* __restrict__ h0)
{
    __shared__ __align__(16) char buf[BUFB];
    __shared__ float patch[300];
    const int t = threadIdx.x, lane = t & 63, wave = t >> 6;
    const int b = blockIdx.x >> 6, tile = blockIdx.x & 63;
    const int ty = tile >> 3, tx = tile & 7;

    // stage 10x10x3 input patch (halo, zero-padded)
    for (int i = t; i < 300; i += 256){
        int ci = i / 100, rem = i % 100, py = rem / 10, px = rem % 10;
        int gy = ty*8 + py - 1, gx = tx*8 + px - 1;
        patch[i] = (gy >= 0 && gy < 64 && gx >= 0 && gx < 64)
                 ? inp[((b*3 + ci) << 12) + (gy << 6) + gx] : 0.f;
    }
    __syncthreads();

    // build conv B operand: row m (pixel), 32 K-slots (64B), act-layout slot mapping
    {
        int m = t >> 2, q = t & 3;
        int my = m >> 3, mx = m & 7;
        ushort_t vals[8];
        #pragma unroll
        for (int j = 0; j < 8; ++j){
            int k = 4*q + (j & 3) + ((j >> 2) << 4);
            float v = 0.f;
            if (k < 27){
                int ci = k / 9, r = k % 9;
                v = patch[ci*100 + (my + r/3)*10 + (mx + r%3)];
            }
            vals[j] = f2h(v);
        }
        u64x2 st;
        st[0] = (unsigned long long)vals[0] | ((unsigned long long)vals[1] << 16)
              | ((unsigned long long)vals[2] << 32) | ((unsigned long long)vals[3] << 48);
        st[1] = (unsigned long long)vals[4] | ((unsigned long long)vals[5] << 16)
              | ((unsigned long long)vals[6] << 32) | ((unsigned long long)vals[7] << 48);
        *(u64x2*)(buf + m*ROWB + ((q*16) ^ ((m & 7) << 4))) = st;
    }
    __syncthreads();

    const int l15 = lane & 15, g = lane >> 4;
    const int swz = (l15 & 7) << 4;
    f32x4 acc[4][4];

    // conv MFMA: acc = convb + Wconv . patch (1 kc)
    #pragma unroll
    for (int nt = 0; nt < 4; ++nt){
        f32x4 bv = *(const f32x4*)(convb + (wave*4 + nt)*16 + 4*g);
        #pragma unroll
        for (int mg = 0; mg < 4; ++mg) acc[mg][nt] = bv;
    }
    {
        const ushort_t* packC = packW + 270336;
        const int lofs = (wave*4*64 + lane)*8;
        f16x8 wc[4], af[4];
        #pragma unroll
        for (int nt = 0; nt < 4; ++nt) wc[nt] = *(const f16x8*)(packC + lofs + nt*512);
        #pragma unroll
        for (int mg = 0; mg < 4; ++mg)
            af[mg] = *(const f16x8*)(buf + (mg*16 + l15)*ROWB + ((g*16) ^ swz));
        #pragma unroll
        for (int mg = 0; mg < 4; ++mg)
            #pragma unroll
            for (int nt = 0; nt < 4; ++nt)
                acc[mg][nt] = __builtin_amdgcn_mfma_f32_16x16x32_f16(wc[nt], af[mg], acc[mg][nt], 0, 0, 0);
    }
    __syncthreads();   // conv B reads done before overwriting rows

    // store feat (NO relu) into buf, unified swizzle
    {
        const int wsw = swz ^ (wave << 4);
        #pragma unroll
        for (int mg = 0; mg < 4; ++mg){
            char* row = buf + (mg*16 + l15)*ROWB;
            #pragma unroll
            for (int i = 0; i < 2; ++i){
                const int kb = 2*wave + i;
                f32x4 a0 = acc[mg][2*i], a1 = acc[mg][2*i + 1];
                u32x4 st;
                st[0] = pkrtz(a0[0], a0[1]);
                st[1] = pkrtz(a0[2], a0[3]);
                st[2] = pkrtz(a1[0], a1[1]);
                st[3] = pkrtz(a1[2], a1[3]);
                *(u32x4*)(row + ((kb*64 + 16*g) ^ wsw)) = st;
            }
        }
    }
    __syncthreads();

    // L0: h0 = feat . W_in[0:256]  (8 kc, zero init, depth-2 weight prefetch)
    #pragma unroll
    for (int nt = 0; nt < 4; ++nt)
        #pragma unroll
        for (int mg = 0; mg < 4; ++mg) acc[mg][nt] = (f32x4){0.f,0.f,0.f,0.f};
    {
        const int lofs = (wave*256 + lane)*8;
        f16x8 wA[4], wB[4], aP0[4], aP1[4];
        #pragma unroll
        for (int nt = 0; nt < 4; ++nt){
            wA[nt] = *(const f16x8*)(packW + lofs + nt*512);
            wB[nt] = *(const f16x8*)(packW + lofs + 8192 + nt*512);
        }
        {
            const int o2 = (g*16) ^ swz;
            #pragma unroll
            for (int mg = 0; mg < 4; ++mg)
                aP0[mg] = *(const f16x8*)(buf + (mg*16 + l15)*ROWB + o2);
        }
        #pragma unroll
        for (int kc = 0; kc < 8; ++kc){
            if (kc + 1 < 8){
                const int o2 = ((kc + 1)*64 + g*16) ^ swz ^ ((((kc + 1) >> 1) & 3) << 4);
                if ((kc & 1) == 0){
                    #pragma unroll
                    for (int mg = 0; mg < 4; ++mg)
                        aP1[mg] = *(const f16x8*)(buf + (mg*16 + l15)*ROWB + o2);
                } else {
                    #pragma unroll
                    for (int mg = 0; mg < 4; ++mg)
                        aP0[mg] = *(const f16x8*)(buf + (mg*16 + l15)*ROWB + o2);
                }
            }
            if ((kc & 1) == 0){
                #pragma unroll
                for (int mg = 0; mg < 4; ++mg)
                    #pragma unroll
                    for (int nt = 0; nt < 4; ++nt)
                        acc[mg][nt] = __builtin_amdgcn_mfma_f32_16x16x32_f16(wA[nt], aP0[mg], acc[mg][nt], 0, 0, 0);
            } else {
                #pragma unroll
                for (int mg = 0; mg < 4; ++mg)
                    #pragma unroll
                    for (int nt = 0; nt < 4; ++nt)
                        acc[mg][nt] = __builtin_amdgcn_mfma_f32_16x16x32_f16(wB[nt], aP1[mg], acc[mg][nt], 0, 0, 0);
            }
            if (kc + 2 < 8){
                const ushort_t* pf = packW + lofs + (kc + 2)*8192;
                if ((kc & 1) == 0){
                    #pragma unroll
                    for (int nt = 0; nt < 4; ++nt) wA[nt] = *(const f16x8*)(pf + nt*512);
                } else {
                    #pragma unroll
                    for (int nt = 0; nt < 4; ++nt) wB[nt] = *(const f16x8*)(pf + nt*512);
                }
            }
        }
    }
    // store h0 (NO bias, NO relu): global permc'd rows, linear chunk positions
    #pragma unroll
    for (int mg = 0; mg < 4; ++mg){
        const int m = mg*16 + l15;
        const int p = ((ty*8 + (m >> 3)) << 6) + tx*8 + (m & 7);
        char* row = (char*)(h0 + (((b<<12) + p)<<8));
        #pragma unroll
        for (int i = 0; i < 2; ++i){
            const int kb = 2*wave + i;
            f32x4 a0 = acc[mg][2*i], a1 = acc[mg][2*i + 1];
            u32x4 st;
            st[0] = pkrtz(a0[0], a0[1]);
            st[1] = pkrtz(a0[2], a0[3]);
            st[2] = pkrtz(a1[0], a1[1]);
            st[3] = pkrtz(a1[2], a1[3]);
            *(u32x4*)(row + kb*64 + 16*g) = st;
        }
    }
}

// ---------------- fused MLP layer, TRANSPOSED, IN-PLACE single buffer -------------------
template<int KC, bool HAS_NEXT, bool STORE>
__device__ __forceinline__ void mlp_layer(const ushort_t* __restrict__ wfrag,
        const ushort_t* __restrict__ nextw,
        const float* __restrict__ bias, char* __restrict__ buf,
        int lane, int wave, f16x8 (&wP0)[4], f16x8 (&wP1)[4], f32x4 (&acc)[4][4])
{
    const int l15 = lane & 15, g = lane >> 4;
    const int swz  = (l15 & 7) << 4;
    const int aoffg = g*16;
    #pragma unroll
    for (int nt = 0; nt < 4; ++nt){
        f32x4 bv = *(const f32x4*)(bias + (wave*4 + nt)*16 + 4*g);
        #pragma unroll
        for (int mg = 0; mg < 4; ++mg) acc[mg][nt] = bv;
    }
    const int lofs = (wave*4*64 + lane)*8;
    f16x8 aP0[4], aP1[4];
    {
        const int o2 = aoffg ^ swz;
        #pragma unroll
        for (int mg = 0; mg < 4; ++mg)
            aP0[mg] = *(const f16x8*)(buf + (mg*16 + l15)*ROWB + o2);
    }
    #pragma unroll
    for (int kc = 0; kc < KC; ++kc){
        const ushort_t* pfw = nullptr;
        if (kc + 2 < KC)   pfw = wfrag + lofs + (kc + 2)*8192;
        else if (HAS_NEXT) pfw = nextw + lofs + (kc + 2 - KC)*8192;
        const bool la = (kc + 1 < KC);
        if (la){
            const int o2 = ((kc + 1)*64 + aoffg) ^ swz ^ ((((kc + 1) >> 1) & 3) << 4);
            if ((kc & 1) == 0){
                #pragma unroll
                for (int mg = 0; mg < 4; ++mg)
                    aP1[mg] = *(const f16x8*)(buf + (mg*16 + l15)*ROWB + o2);
            } else {
                #pragma unroll
                for (int mg = 0; mg < 4; ++mg)
                    aP0[mg] = *(const f16x8*)(buf + (mg*16 + l15)*ROWB + o2);
            }
        }
        __builtin_amdgcn_s_setprio(1);
        if ((kc & 1) == 0){
            #pragma unroll
            for (int mg = 0; mg < 4; ++mg)
                #pragma unroll
                for (int nt = 0; nt < 4; ++nt)
                    acc[mg][nt] = __builtin_amdgcn_mfma_f32_16x16x32_f16(wP0[nt], aP0[mg], acc[mg][nt], 0, 0, 0);
        } else {
            #pragma unroll
            for (int mg = 0; mg < 4; ++mg)
                #pragma unroll
                for (int nt = 0; nt < 4; ++nt)
                    acc[mg][nt] = __builtin_amdgcn_mfma_f32_16x16x32_f16(wP1[nt], aP1[mg], acc[mg][nt], 0, 0, 0);
        }
        __builtin_amdgcn_s_setprio(0);
        if (pfw){
            if ((kc & 1) == 0){
                #pragma unroll
                for (int nt = 0; nt < 4; ++nt) wP0[nt] = *(const f16x8*)(pfw + nt*512);
            } else {
                #pragma unroll
                for (int nt = 0; nt < 4; ++nt) wP1[nt] = *(const f16x8*)(pfw + nt*512);
            }
        }
    }
    __syncthreads();   // all waves' reads of buf drained
    if (STORE){
        const int wsw = swz ^ (wave << 4);   // log>>7 = kb>>1 = wave (const per wave)
        #pragma unroll
        for (int mg = 0; mg < 4; ++mg){
            char* row = buf + (mg*16 + l15)*ROWB;
            #pragma unroll
            for (int i = 0; i < 2; ++i){
                const int kb = 2*wave + i;
                f32x4 a0 = acc[mg][2*i], a1 = acc[mg][2*i + 1];
                u32x4 st;
                st[0] = pk_relu2(pkrtz(a0[0], a0[1]));
                st[1] = pk_relu2(pkrtz(a0[2], a0[3]));
                st[2] = pk_relu2(pkrtz(a1[0], a1[1]));
                st[3] = pk_relu2(pkrtz(a1[2], a1[3]));
                *(u32x4*)(row + ((kb*64 + 16*g) ^ wsw)) = st;
            }
        }
        __syncthreads();   // stores visible before next layer reads
    }
}

// ---------------- main fused kernel: 16 pixels x 4 corners per block; in-kernel combine ----
__global__ __launch_bounds__(256, 3) void liif_k(
        const float* __restrict__ coord, const float* __restrict__ cell,
        const float* __restrict__ b_in, const float* __restrict__ b_hid,
        const float* __restrict__ w_out, const float* __restrict__ b_out,
        const ushort_t* __restrict__ h0, const ushort_t* __restrict__ packW,
        float* __restrict__ out)
{
    __shared__ __align__(16) char buf[BUFB];   // 36864 B -> 3 blocks/CU
    __shared__ float sarea[64];
    const int t = threadIdx.x, lane = t & 63, wave = t >> 6;   // wave in [0,4)
    const int bi = blockIdx.x;
    const int b = bi >> 12;
    const int t12 = bi & 4095;
    const int th = t12 >> 6, tw = t12 & 63;   // 64x64 tiles of 4x4 pixels

    // --- prologue loads: L0-extras weights (kc8) + L1 kc0/kc1 ---
    f16x8 wX[4], wA[4], wB[4];
    const ushort_t* L1 = packW + 73728;
    {
        const int lofs = (wave*256 + lane)*8;
        #pragma unroll
        for (int nt = 0; nt < 4; ++nt){
            wX[nt] = *(const f16x8*)(packW + 65536 + lofs + nt*512);
            wA[nt] = *(const f16x8*)(L1 + lofs + nt*512);
            wB[nt] = *(const f16x8*)(L1 + 8192 + nt*512 + lofs);
        }
    }

    // --- setup: gather h0 rows + extras + area (4 threads per row, 128B each) ---
    {
        int m = t >> 2, q = t & 3;
        int v = m >> 4, pix = m & 15;
        int qh = th*4 + (pix >> 2), qw = tw*4 + (pix & 3);
        int cidx = (((b<<8) + qh)<<8) + qw;
        float c0 = coord[cidx*2], c1 = coord[cidx*2 + 1];
        float ch = c0 + ((v & 2) ? 0.015625f : -0.015625f); ch = ch + 1e-6f;
        ch = fminf(fmaxf(ch, -1.f + 1e-6f), 1.f - 1e-6f);
        float cw = c1 + ((v & 1) ? 0.015625f : -0.015625f); cw = cw + 1e-6f;
        cw = fminf(fmaxf(cw, -1.f + 1e-6f), 1.f - 1e-6f);
        int ih = (int)floorf((ch + 1.f)*64.f*0.5f); ih = ih < 0 ? 0 : (ih > 63 ? 63 : ih);
        int iw = (int)floorf((cw + 1.f)*64.f*0.5f); iw = iw < 0 ? 0 : (iw > 63 ? 63 : iw);
        char* drow = buf + m*ROWB;
        int sw = ((m & 7) << 4) ^ (q << 4);   // unified swizzle: q = log>>7
        const u64x2* src = (const u64x2*)(h0 + ((((b<<6) + ih)<<6) + iw)*256 + q*64);
        #pragma unroll
        for (int c = 0; c < 8; ++c)
            *(u64x2*)(drow + ((q*128 + c*16) ^ sw)) = src[c];
        if (q == 0){
            float qch = (2.f*(float)ih + 1.f)*(1.f/64.f) - 1.f;
            float qcw = (2.f*(float)iw + 1.f)*(1.f/64.f) - 1.f;
            float relh = (c0 - qch)*64.f, relw = (c1 - qcw)*64.f;
            float rch = cell[b*2]*64.f, rcw = cell[b*2 + 1]*64.f;
            unsigned long long ex = (unsigned long long)f2h(relh)
                | ((unsigned long long)f2h(relw) << 16)
                | ((unsigned long long)f2h(rch)  << 32)
                | ((unsigned long long)f2h(rcw)  << 48);
            u64x2 e; e[0] = ex; e[1] = 0;
            u64x2 z; z[0] = 0;  z[1] = 0;
            int sw2 = (m & 3) << 4;
            #pragma unroll
            for (int c = 1; c < 4; ++c)
                *(u64x2*)(drow + 512 + ((c*16) ^ sw2)) = z;
            *(u64x2*)(drow + 512 + sw2) = e;
            sarea[m] = fabsf(relh*relw) + 1e-9f;
        }
    }
    __syncthreads();

    f32x4 acc[4][4];
    // --- L0': bias + extras-MFMA (1 kc) + packed-fp16 h0 add + ReLU, store in place ---
    {
        const int l15 = lane & 15, g = lane >> 4;
        const int swz  = (l15 & 7) << 4;
        const int swz2 = (l15 & 3) << 4;
        const int wsw  = swz ^ (wave << 4);
        #pragma unroll
        for (int nt = 0; nt < 4; ++nt){
            f32x4 bv = *(const f32x4*)(b_in + (wave*4 + nt)*16 + 4*g);
            #pragma unroll
            for (int mg = 0; mg < 4; ++mg) acc[mg][nt] = bv;
        }
        f16x8 af[4];
        {
            const int o2 = 512 + ((g*16) ^ swz2);
            #pragma unroll
            for (int mg = 0; mg < 4; ++mg)
                af[mg] = *(const f16x8*)(buf + (mg*16 + l15)*ROWB + o2);
        }
        #pragma unroll
        for (int mg = 0; mg < 4; ++mg)
            #pragma unroll
            for (int nt = 0; nt < 4; ++nt)
                acc[mg][nt] = __builtin_amdgcn_mfma_f32_16x16x32_f16(wX[nt], af[mg], acc[mg][nt], 0, 0, 0);
        #pragma unroll
        for (int mg = 0; mg < 4; ++mg){
            char* row = buf + (mg*16 + l15)*ROWB;
            #pragma unroll
            for (int i = 0; i < 2; ++i){
                const int kb = 2*wave + i;
                u32x4 hv = *(const u32x4*)(row + ((kb*64 + 16*g) ^ wsw));
                f32x4 a0 = acc[mg][2*i], a1 = acc[mg][2*i + 1];
                u32x4 st;
                st[0] = pk_relu2(pk_add2(pkrtz(a0[0], a0[1]), hv[0]));
                st[1] = pk_relu2(pk_add2(pkrtz(a0[2], a0[3]), hv[1]));
                st[2] = pk_relu2(pk_add2(pkrtz(a1[0], a1[1]), hv[2]));
                st[3] = pk_relu2(pk_add2(pkrtz(a1[2], a1[3]), hv[3]));
                *(u32x4*)(row + ((kb*64 + 16*g) ^ wsw)) = st;
            }
        }
        __syncthreads();
    }

    // --- 3 MFMA layers (in-place; even KC -> no parity swap) ---
    const ushort_t* L2 = packW + 73728 + 65536;
    const ushort_t* L3 = packW + 73728 + 131072;
    mlp_layer<8, true , true >(L1, L2,      b_hid,       buf, lane, wave, wA, wB, acc);
    mlp_layer<8, true , true >(L2, L3,      b_hid + 256, buf, lane, wave, wA, wB, acc);
    mlp_layer<8, false, false>(L3, nullptr, b_hid + 512, buf, lane, wave, wA, wB, acc);

    // --- fused out layer + ensemble combine + softmax ---
    {
        const int l15 = lane & 15, g = lane >> 4;
        float s0[4] = {0.f,0.f,0.f,0.f}, s1[4] = {0.f,0.f,0.f,0.f};
        #pragma unroll
        for (int j = 0; j < 4; ++j){
            int nb = wave*64 + j*16 + 4*g;
            f32x4 w01 = *(const f32x4*)(w_out + nb*2);
            f32x4 w23 = *(const f32x4*)(w_out + nb*2 + 4);
            #pragma unroll
            for (int mg = 0; mg < 4; ++mg){
                float v0 = fmaxf(acc[mg][j][0], 0.f);
                float v1 = fmaxf(acc[mg][j][1], 0.f);
                float v2 = fmaxf(acc[mg][j][2], 0.f);
                float v3 = fmaxf(acc[mg][j][3], 0.f);
                s0[mg] += v0*w01[0] + v1*w01[2] + v2*w23[0] + v3*w23[2];
                s1[mg] += v0*w01[1] + v1*w01[3] + v2*w23[1] + v3*w23[3];
            }
        }
        float2* stage  = (float2*)buf;          // [wave][mg*16+pix], 2 KB
        float2* stage2 = (float2*)(buf + 2048); // [mg*16+pix], 512 B
        #pragma unroll
        for (int mg = 0; mg < 4; ++mg){
            s0[mg] += __shfl_xor(s0[mg], 16); s0[mg] += __shfl_xor(s0[mg], 32);
            s1[mg] += __shfl_xor(s1[mg], 16); s1[mg] += __shfl_xor(s1[mg], 32);
            if (lane < 16){
                float2 pr; pr.x = s0[mg]; pr.y = s1[mg];
                stage[wave*64 + mg*16 + l15] = pr;
            }
        }
        __syncthreads();
        if (t < 64){
            float2 p0 = stage[t], p1 = stage[64 + t], p2 = stage[128 + t], p3 = stage[192 + t];
            float2 pr;
            pr.x = p0.x + p1.x + p2.x + p3.x;
            pr.y = p0.y + p1.y + p2.y + p3.y;
            stage2[t] = pr;
        }
        __syncthreads();
        if (t < 16){
            float2 pv[4]; float a[4];
            #pragma unroll
            for (int v = 0; v < 4; ++v){
                pv[v] = stage2[v*16 + t];
                a[v]  = sarea[v*16 + t];
            }
            float tot = a[0] + a[1] + a[2] + a[3];
            float w0 = a[3]/tot, w1 = a[2]/tot, w2 = a[1]/tot, w3 = a[0]/tot;
            float r0 = pv[0].x*w0 + pv[1].x*w1 + pv[2].x*w2 + pv[3].x*w3 + b_out[0];
            float r1 = pv[0].y*w0 + pv[1].y*w1 + pv[2].y*w2 + pv[3].y*w3 + b_out[1];
            float mx = fmaxf(r0, r1);
            float e0 = expf(r0 - mx), e1 = expf(r1 - mx);
            float inv = 1.f/(e0 + e1);
            int qh = th*4 + (t >> 2), qw = tw*4 + (t & 3);
            int qidx = (qh << 8) + qw;
            out[(b<<17) + qidx]         = e0*inv;
            out[(b<<17) + 65536 + qidx] = e1*inv;
        }
    }
}

extern "C" void kernel_launch(void* const* d_in, const int* in_sizes, int n_in,
                              void* d_out, int out_size, void* d_ws, size_t ws_size,
                              hipStream_t stream)
{
    const float* inp   = (const float*)d_in[0];
    const float* coord = (const float*)d_in[1];
    const float* cell  = (const float*)d_in[2];
    const float* convw = (const float*)d_in[3];
    const float* convb = (const float*)d_in[4];
    const float* w_in  = (const float*)d_in[5];
    const float* b_in  = (const float*)d_in[6];
    const float* w_hid = (const float*)d_in[7];
    const float* b_hid = (const float*)d_in[8];
    const float* w_out = (const float*)d_in[9];
    const float* b_out = (const float*)d_in[10];
    (void)in_sizes; (void)n_in; (void)out_size; (void)ws_size;

    char* ws = (char*)d_ws;
    ushort_t* h0    = (ushort_t*)ws;                                  // 4,194,304 B
    ushort_t* packW = (ushort_t*)(ws + 4194304);                      //   557,056 B
    float* out = (float*)d_out;

    pack_k<<<dim3(1088), dim3(256), 0, stream>>>(w_in, w_hid, convw, packW);
    convl0_k<<<dim3(128), dim3(256), 0, stream>>>(inp, convb, packW, h0);
    liif_k<<<dim3(8192), dim3(256), 0, stream>>>(coord, cell, b_in, b_hid,
                                                 w_out, b_out, h0, packW, out);
}